// Round 1
// baseline (276.364 us; speedup 1.0000x reference)
//
#include <hip/hip_runtime.h>
#include <math.h>

#define BLK 256
#define EPS_EYE 1e-7f

__global__ __launch_bounds__(BLK) void gaussian_cov_kernel(
    const float* __restrict__ scaling,
    const float* __restrict__ rotation,
    float* __restrict__ out,
    int N)
{
    // Staging buffers: scaling in (3 floats/pt), cov out (9 floats/pt).
    __shared__ __align__(16) float lds_s[BLK * 3];
    __shared__ __align__(16) float lds_o[BLK * 9];

    const int tid = threadIdx.x;
    const long long base = (long long)blockIdx.x * BLK;
    const int nPts = min(BLK, (int)((long long)N - base));
    const int nFloats = nPts * 3;

    // ---- Stage scaling via coalesced float4 loads ----
    // base*3 floats offset = 768*blockIdx floats -> 16B aligned.
    const float4* s4 = (const float4*)(scaling + base * 3);
    const int nF4 = nFloats >> 2;
    for (int i = tid; i < nF4; i += BLK) {
        float4 v = s4[i];
        lds_s[4 * i + 0] = v.x;
        lds_s[4 * i + 1] = v.y;
        lds_s[4 * i + 2] = v.z;
        lds_s[4 * i + 3] = v.w;
    }
    for (int i = (nF4 << 2) + tid; i < nFloats; i += BLK) {
        lds_s[i] = scaling[base * 3 + i];
    }
    __syncthreads();

    // ---- Per-point math (fp32 end-to-end, matches reference exactly) ----
    if (tid < nPts) {
        const float4 q = ((const float4*)rotation)[base + tid];
        float x = q.x, y = q.y, z = q.z, w = q.w;
        const float inv = 1.0f / sqrtf(x * x + y * y + z * z + w * w);
        x *= inv; y *= inv; z *= inv; w *= inv;

        const float sx = expf(lds_s[tid * 3 + 0]);
        const float sy = expf(lds_s[tid * 3 + 1]);
        const float sz = expf(lds_s[tid * 3 + 2]);

        const float R00 = 1.0f - 2.0f * (y * y + z * z);
        const float R01 = 2.0f * (x * y - w * z);
        const float R02 = 2.0f * (x * z + w * y);
        const float R10 = 2.0f * (x * y + w * z);
        const float R11 = 1.0f - 2.0f * (x * x + z * z);
        const float R12 = 2.0f * (y * z - w * x);
        const float R20 = 2.0f * (x * z - w * y);
        const float R21 = 2.0f * (y * z + w * x);
        const float R22 = 1.0f - 2.0f * (x * x + y * y);

        // L = R * diag(s)
        const float l00 = R00 * sx, l01 = R01 * sy, l02 = R02 * sz;
        const float l10 = R10 * sx, l11 = R11 * sy, l12 = R12 * sz;
        const float l20 = R20 * sx, l21 = R21 * sy, l22 = R22 * sz;

        // cov = L * L^T  (exactly symmetric -> symmetrization is a no-op)
        const float c00 = l00 * l00 + l01 * l01 + l02 * l02 + EPS_EYE;
        const float c01 = l00 * l10 + l01 * l11 + l02 * l12;
        const float c02 = l00 * l20 + l01 * l21 + l02 * l22;
        const float c11 = l10 * l10 + l11 * l11 + l12 * l12 + EPS_EYE;
        const float c12 = l10 * l20 + l11 * l21 + l12 * l22;
        const float c22 = l20 * l20 + l21 * l21 + l22 * l22 + EPS_EYE;

        float* o = lds_o + tid * 9;  // stride-9 across lanes: 2-way bank alias (free)
        o[0] = c00; o[1] = c01; o[2] = c02;
        o[3] = c01; o[4] = c11; o[5] = c12;
        o[6] = c02; o[7] = c12; o[8] = c22;
    }
    __syncthreads();

    // ---- Coalesced float4 stores from LDS ----
    // base*9 floats offset = 2304*blockIdx floats -> 16B aligned.
    const int nOut = nPts * 9;
    float4* o4 = (float4*)(out + base * 9);
    const int nO4 = nOut >> 2;
    const float4* lo4 = (const float4*)lds_o;
    for (int i = tid; i < nO4; i += BLK) {
        o4[i] = lo4[i];
    }
    for (int i = (nO4 << 2) + tid; i < nOut; i += BLK) {
        out[base * 9 + i] = lds_o[i];
    }
}

extern "C" void kernel_launch(void* const* d_in, const int* in_sizes, int n_in,
                              void* d_out, int out_size, void* d_ws, size_t ws_size,
                              hipStream_t stream) {
    const float* scaling  = (const float*)d_in[0];
    const float* rotation = (const float*)d_in[1];
    float* out = (float*)d_out;
    const int N = in_sizes[0] / 3;
    const int blocks = (N + BLK - 1) / BLK;
    gaussian_cov_kernel<<<blocks, BLK, 0, stream>>>(scaling, rotation, out, N);
}